// Round 16
// baseline (95.821 us; speedup 1.0000x reference)
//
#include <hip/hip_runtime.h>
#include <hip/hip_bf16.h>
#include <math.h>

#define BN_EPS 1e-5f
#define B_  96
#define N_  20
#define D_  2048
#define K_  10
#define M_  (B_*N_)   // 1920
#define R_  (2*D_)    // 4096

typedef __attribute__((ext_vector_type(8))) short bf16x8;
typedef __attribute__((ext_vector_type(4))) float f32x4;
typedef __attribute__((ext_vector_type(8))) unsigned short ushort8;

static __device__ __forceinline__ unsigned short f2bf(float f) {
  unsigned int u = __builtin_bit_cast(unsigned int, f);
  u = u + 0x7fffu + ((u >> 16) & 1u);   // RNE (finite inputs only)
  return (unsigned short)(u >> 16);
}

#define GLOAD_LDS16(g, l) \
  __builtin_amdgcn_global_load_lds((const __attribute__((address_space(1))) void*)(g), \
                                   (__attribute__((address_space(3))) void*)(l), 16, 0, 0)

// ------- kernel 1: heterogeneous prep (2-dispatch total plan) --------------
// blocks 0..239: gram — 8 (b,n) wave tasks each (240*8=1920 exact), THEN
//   cast_x for this block's 2048-chunk slice (x hot in L1/L2; 4-chunk ILP).
// blocks 240..751: cast_w — 2048 chunks each, 4/thread ILP (round-15 pattern).
// Rationale (round-15 lesson): separation cost ~15 us in gaps + lost overlap;
// latency-bound gram and BW-bound casts co-schedule on every CU.
__global__ __launch_bounds__(512) void prep_kernel(const float* __restrict__ x,
                                                   const float* __restrict__ cw,
                                                   float* __restrict__ innr_g,
                                                   unsigned short* __restrict__ Xb,
                                                   unsigned short* __restrict__ Wn)
{
  int t = threadIdx.x;
  if (blockIdx.x >= 240) {
    // ---- cast_w: Wn[r][k], r=2*o+h: h=0 -> cw[o][k], h=1 -> cw[o][2048+k]
    int q = (blockIdx.x - 240) * 512 + t;        // 512*512*4 = 1048576 exact
    const float* sp[4]; ushort8* dp[4];
    #pragma unroll
    for (int s = 0; s < 4; ++s) {
      int j = q + s * 262144;
      int r = j >> 8, k = (j & 255) * 8;
      sp[s] = cw + (size_t)(r >> 1) * R_ + ((r & 1) << 11) + k;
      dp[s] = (ushort8*)Wn + j;
    }
    float4 a[4], c[4];
    #pragma unroll
    for (int s = 0; s < 4; ++s) { a[s] = *(const float4*)sp[s]; c[s] = *(const float4*)(sp[s] + 4); }
    #pragma unroll
    for (int s = 0; s < 4; ++s) {
      ushort8 o = { f2bf(a[s].x), f2bf(a[s].y), f2bf(a[s].z), f2bf(a[s].w),
                    f2bf(c[s].x), f2bf(c[s].y), f2bf(c[s].z), f2bf(c[s].w) };
      *dp[s] = o;
    }
    return;
  }
  // ---- gram: wave task = (b, n); innr[n][m] for m>=n ----
  int w = t >> 6, lane = t & 63;
  int task = blockIdx.x * 8 + w;
  int b = task / N_, n = task % N_;
  const float* xb = x + (size_t)b * N_ * D_;
  const float4* pn = (const float4*)(xb + n * D_);
  float4 c[8];
  #pragma unroll
  for (int j = 0; j < 8; ++j) c[j] = pn[lane + 64*j];
  float* ig = innr_g + b * (N_*N_);
  for (int m = n; m < N_; ++m) {
    const float4* pm = (const float4*)(xb + m * D_);
    float s0 = 0.f, s1 = 0.f, s2 = 0.f, s3 = 0.f;
    #pragma unroll
    for (int j = 0; j < 8; ++j) {
      float4 v = pm[lane + 64*j];
      float d = fmaf(c[j].x, v.x, fmaf(c[j].y, v.y,
                fmaf(c[j].z, v.z, c[j].w * v.w)));
      if      ((j&3)==0) s0 += d;
      else if ((j&3)==1) s1 += d;
      else if ((j&3)==2) s2 += d;
      else               s3 += d;
    }
    float s = (s0 + s1) + (s2 + s3);
    #pragma unroll
    for (int off = 32; off > 0; off >>= 1)
      s += __shfl_xor(s, off, 64);
    if (lane == 0) { ig[n*N_ + m] = s; ig[m*N_ + n] = s; }
  }
  // ---- cast_x slice for this block: chunks [bIdx*2048, bIdx*2048+2048) ----
  {
    int q = blockIdx.x * 2048 + t;               // 240*2048 = 491520 exact
    const float* sp[4]; ushort8* dp[4];
    #pragma unroll
    for (int s = 0; s < 4; ++s) {
      int i = q + s * 512;
      sp[s] = x + (size_t)i * 8;
      dp[s] = (ushort8*)Xb + i;
    }
    float4 a[4], cc[4];
    #pragma unroll
    for (int s = 0; s < 4; ++s) { a[s] = *(const float4*)sp[s]; cc[s] = *(const float4*)(sp[s] + 4); }
    #pragma unroll
    for (int s = 0; s < 4; ++s) {
      ushort8 o = { f2bf(a[s].x), f2bf(a[s].y), f2bf(a[s].z), f2bf(a[s].w),
                    f2bf(cc[s].x), f2bf(cc[s].y), f2bf(cc[s].z), f2bf(cc[s].w) };
      *dp[s] = o;
    }
  }
}

// ---------------- kernel 2: fused bf16 MFMA GEMM + topk + BN/ReLU/max ------
// K-loop EXACT round-11 (proven 44.1 us). NEW: top-k computed IN-BLOCK from
// innr_g after the K-loop (1600-float LDS load + 80-thread select; 32x
// redundant across by-blocks but ~1-2 us) — kills the topk dispatch, its
// launch gap, and the nn_idx global round-trip.
__global__ __launch_bounds__(256, 3) void fused_gemm(
    const unsigned short* __restrict__ Xb, const unsigned short* __restrict__ Wn,
    const float* __restrict__ innr_g, const float* __restrict__ conv_b,
    const float* __restrict__ gamma, const float* __restrict__ beta,
    const float* __restrict__ mean, const float* __restrict__ var,
    float* __restrict__ out)
{
  __shared__ __align__(16) char smem[53248];
  // K-loop: buffer sel at smem+sel*26624 (As 10240 B + Bs 16384 B each)
  float* Cl   = (float*)smem;                   // [80][128] f32, 0..40960
  int*   idxl = (int*)(smem + 40960);           // [4][200] int, 40960..44160
  float* adjt = (float*)(smem + 44160);         // [4][400] f32, 44160..50560
  float* dl   = (float*)(smem + 50560);         // [4][20]  f32, 50560..50880

  // bijective XCD-chunk swizzle (768 % 8 == 0)
  int flat = blockIdx.y * 24 + blockIdx.x;
  int nf = (flat & 7) * 96 + (flat >> 3);
  int bx = nf % 24, by = nf / 24;

  int t = threadIdx.x, lane = t & 63, w = t >> 6;  // w = wr (0..3)
  int m0 = bx * 80, b0 = bx * 4;
  int r0 = by * 128, o0 = by * 64;
  int rowsel = lane & 15, ksel = lane >> 4;

  f32x4 acc[5][2] = {};

  auto stage = [&](int sel, int k0) {
    unsigned short* Asb = (unsigned short*)(smem + sel*26624);
    unsigned short* Bsb = (unsigned short*)(smem + sel*26624 + 10240);
    #pragma unroll
    for (int i = 0; i < 3; ++i) {                 // A: 640 16B-chunks
      int fl = i*256 + t;
      if (fl < 640) {
        int row = fl >> 3, kc = fl & 7;
        GLOAD_LDS16(Xb + (size_t)(m0 + row) * D_ + k0 + ((kc ^ (row & 7)) << 3),
                    Asb + fl*8);
      }
    }
    #pragma unroll
    for (int i = 0; i < 4; ++i) {                 // B: 1024 16B-chunks
      int fl = i*256 + t;
      int row = fl >> 3, kc = fl & 7;
      GLOAD_LDS16(Wn + (size_t)(r0 + row) * D_ + k0 + ((kc ^ (row & 7)) << 3),
                  Bsb + fl*8);
    }
  };

  auto compute = [&](int sel) {
    unsigned short* Asb = (unsigned short*)(smem + sel*26624);
    unsigned short* Bsb = (unsigned short*)(smem + sel*26624 + 10240);
    #pragma unroll
    for (int ks = 0; ks < 2; ++ks) {
      int swz = ((ks*4 + ksel) ^ (rowsel & 7)) << 3;   // tile offsets are 16-mult
      bf16x8 a[5], bfr[2];
      #pragma unroll
      for (int mi = 0; mi < 5; ++mi)
        a[mi] = *(const bf16x8*)(Asb + (mi*16 + rowsel)*64 + swz);
      #pragma unroll
      for (int ri = 0; ri < 2; ++ri)
        bfr[ri] = *(const bf16x8*)(Bsb + (w*32 + ri*16 + rowsel)*64 + swz);
      #pragma unroll
      for (int mi = 0; mi < 5; ++mi)
        #pragma unroll
        for (int ri = 0; ri < 2; ++ri)
          acc[mi][ri] = __builtin_amdgcn_mfma_f32_16x16x32_bf16(a[mi], bfr[ri], acc[mi][ri], 0, 0, 0);
    }
  };

  stage(0, 0);
  for (int kt = 0; kt < D_/64; ++kt) {
    __syncthreads();                              // drains stage issued last step
    if (kt + 1 < D_/64) stage((kt+1) & 1, (kt+1)*64);
    compute(kt & 1);
  }
  __syncthreads();                                // all buffer reads done

  // ---- epilogue phase 1: acc -> Cl; raw innr + diag -> LDS ----
  #pragma unroll
  for (int mi = 0; mi < 5; ++mi)
    #pragma unroll
    for (int ri = 0; ri < 2; ++ri)
      #pragma unroll
      for (int rg = 0; rg < 4; ++rg)
        Cl[(mi*16 + ksel*4 + rg)*128 + w*32 + ri*16 + rowsel] = acc[mi][ri][rg];
  for (int i = t; i < 4*N_*N_; i += 256) adjt[i] = innr_g[b0*N_*N_ + i];
  if (t < 4*N_) dl[t] = innr_g[(b0 + t/N_)*N_*N_ + (t%N_)*(N_+1)];
  __syncthreads();

  // ---- phase 2: adj in place (same-thread read/write per element) ----
  for (int i = t; i < 4*N_*N_; i += 256) {
    int bb = i / (N_*N_), p = i % (N_*N_);
    adjt[i] = dl[bb*N_ + p/N_] + dl[bb*N_ + p%N_] - 2.f * adjt[i];
  }
  __syncthreads();

  // ---- phase 3: top-k select (80 tasks; strict < scan = lax.top_k ties) ----
  if (t < 4*N_) {
    int bb = t / N_, n = t % N_;
    const float* row = adjt + bb*N_*N_ + n*N_;
    unsigned mask = 0;
    for (int it = 0; it < K_; ++it) {
      float bv = INFINITY; int bi = 0;
      for (int m = 0; m < N_; ++m) {
        if (!((mask >> m) & 1u)) {
          float v = row[m];
          if (v < bv) { bv = v; bi = m; }
        }
      }
      mask |= 1u << bi;
      idxl[(bb*N_ + n)*K_ + it] = bi;
    }
  }
  __syncthreads();

  // ---- phase 4: BN/ReLU/neighbor-max ----
  int bb = w, oo = lane;               // (batch-in-tile, output-in-tile)
  int og = o0 + oo;
  float invv  = gamma[og] / sqrtf(var[og] + BN_EPS);
  float shift = fmaf(-mean[og], invv, beta[og]);
  float bias  = conv_b[og];
  float best = 0.f;                    // relu identity
  int rbase = bb * N_;
  for (int n = 0; n < N_; ++n) {
    float Pv = Cl[(rbase + n)*128 + oo*2];
    float Qn = Cl[(rbase + n)*128 + oo*2 + 1];
    float aa = Pv - Qn + bias;
    const int* ix = idxl + bb*N_*K_ + n*K_;
    #pragma unroll
    for (int kk = 0; kk < K_; ++kk) {
      int j = ix[kk];
      float v = fmaf(aa + Cl[(rbase + j)*128 + oo*2 + 1], invv, shift);
      best = fmaxf(best, v);
    }
  }
  out[(size_t)(b0 + bb) * D_ + og] = best;
}

extern "C" void kernel_launch(void* const* d_in, const int* in_sizes, int n_in,
                              void* d_out, int out_size, void* d_ws, size_t ws_size,
                              hipStream_t stream)
{
  const float* x      = (const float*)d_in[0];
  const float* conv_w = (const float*)d_in[1];
  const float* conv_b = (const float*)d_in[2];
  const float* gamma  = (const float*)d_in[3];
  const float* beta   = (const float*)d_in[4];
  const float* mean   = (const float*)d_in[5];
  const float* var    = (const float*)d_in[6];

  // workspace: (76800 reserved) | Xb 7864320 | Wn 16777216 | innr_g 153600
  unsigned short* Xb = (unsigned short*)((char*)d_ws + 76800);
  unsigned short* Wn = (unsigned short*)((char*)d_ws + 76800 + (size_t)M_*D_*2);
  float* innr_g = (float*)((char*)d_ws + 76800 + (size_t)M_*D_*2 + (size_t)R_*D_*2);

  prep_kernel<<<752, 512, 0, stream>>>(x, conv_w, innr_g, Xb, Wn);
  fused_gemm<<<dim3(24, 32), 256, 0, stream>>>(
      Xb, Wn, innr_g, conv_b, gamma, beta, mean, var, (float*)d_out);
}

// Round 17
// 92.621 us; speedup vs baseline: 1.0345x; 1.0345x over previous
//
#include <hip/hip_runtime.h>
#include <hip/hip_bf16.h>
#include <math.h>

#define BN_EPS 1e-5f
#define B_  96
#define N_  20
#define D_  2048
#define K_  10
#define M_  (B_*N_)   // 1920
#define R_  (2*D_)    // 4096

typedef __attribute__((ext_vector_type(8))) short bf16x8;
typedef __attribute__((ext_vector_type(4))) float f32x4;
typedef __attribute__((ext_vector_type(8))) unsigned short ushort8;

static __device__ __forceinline__ unsigned short f2bf(float f) {
  unsigned int u = __builtin_bit_cast(unsigned int, f);
  u = u + 0x7fffu + ((u >> 16) & 1u);   // RNE (finite inputs only)
  return (unsigned short)(u >> 16);
}

#define GLOAD_LDS16(g, l) \
  __builtin_amdgcn_global_load_lds((const __attribute__((address_space(1))) void*)(g), \
                                   (__attribute__((address_space(3))) void*)(l), 16, 0, 0)

// ------- kernel 1: knn + topk + cast_x (R12-proven body, cast_w REMOVED) ---
// 96 blocks. Wave w register-caches rows {w, w+8, 16+w (w<4)}, streams each
// m-row once. Then in-block topk (strict-< scan = lax.top_k ties) and cast_x.
__global__ __launch_bounds__(512, 2) void prep_kernel(const float* __restrict__ x,
                                                      int* __restrict__ nn_idx,
                                                      unsigned short* __restrict__ Xb)
{
  int t = threadIdx.x;
  int b = blockIdx.x, w = t >> 6, lane = t & 63;
  __shared__ float innr[N_*N_];
  __shared__ float adjl[N_*N_];
  const float* xb = x + (size_t)b * N_ * D_;
  int n1 = w, n2 = w + 8, n3 = (w < 4) ? 16 + w : -1;
  float4 c1[8], c2[8], c3[8];
  const float4* p1 = (const float4*)(xb + n1 * D_);
  const float4* p2 = (const float4*)(xb + n2 * D_);
  #pragma unroll
  for (int j = 0; j < 8; ++j) { c1[j] = p1[lane + 64*j]; c2[j] = p2[lane + 64*j]; }
  if (n3 >= 0) {
    const float4* p3 = (const float4*)(xb + n3 * D_);
    #pragma unroll
    for (int j = 0; j < 8; ++j) c3[j] = p3[lane + 64*j];
  }
  for (int m = n1; m < N_; ++m) {                // each m-row streamed ONCE
    bool d2 = (m >= n2), d3 = (n3 >= 0) && (m >= n3);   // wave-uniform
    const float4* pm = (const float4*)(xb + m * D_);
    float s1 = 0.f, s2 = 0.f, s3 = 0.f;
    #pragma unroll
    for (int j = 0; j < 8; ++j) {
      float4 v = pm[lane + 64*j];
      s1 = fmaf(c1[j].x, v.x, fmaf(c1[j].y, v.y, fmaf(c1[j].z, v.z, fmaf(c1[j].w, v.w, s1))));
      if (d2) s2 = fmaf(c2[j].x, v.x, fmaf(c2[j].y, v.y, fmaf(c2[j].z, v.z, fmaf(c2[j].w, v.w, s2))));
      if (d3) s3 = fmaf(c3[j].x, v.x, fmaf(c3[j].y, v.y, fmaf(c3[j].z, v.z, fmaf(c3[j].w, v.w, s3))));
    }
    #pragma unroll
    for (int off = 32; off > 0; off >>= 1) {
      s1 += __shfl_xor(s1, off, 64);
      if (d2) s2 += __shfl_xor(s2, off, 64);
      if (d3) s3 += __shfl_xor(s3, off, 64);
    }
    if (lane == 0) {
      innr[n1*N_+m] = s1; innr[m*N_+n1] = s1;
      if (d2) { innr[n2*N_+m] = s2; innr[m*N_+n2] = s2; }
      if (d3) { innr[n3*N_+m] = s3; innr[m*N_+n3] = s3; }
    }
  }
  __syncthreads();
  for (int p = t; p < N_*N_; p += 512) {
    int n = p / N_, m = p % N_;
    adjl[p] = innr[n*N_+n] + innr[m*N_+m] - 2.f * innr[p];
  }
  __syncthreads();
  if (t < N_) {
    int n = t;
    unsigned mask = 0;
    for (int it = 0; it < K_; ++it) {
      float bv = INFINITY; int bi = 0;
      for (int m = 0; m < N_; ++m) {
        if (!((mask >> m) & 1u)) {
          float v = adjl[n*N_+m];
          if (v < bv) { bv = v; bi = m; }
        }
      }
      mask |= 1u << bi;
      nn_idx[(b*N_ + n)*K_ + it] = bi;
    }
  }
  // cast_x for this batch's slice (hot in L1/L2)
  unsigned short* xo = Xb + (size_t)b * N_ * D_;
  for (int i = t; i < N_*D_/8; i += 512) {
    const float4* src = (const float4*)xb + (size_t)i * 2;
    float4 a = src[0], c = src[1];
    ushort8 o = { f2bf(a.x), f2bf(a.y), f2bf(a.z), f2bf(a.w),
                  f2bf(c.x), f2bf(c.y), f2bf(c.z), f2bf(c.w) };
    *((ushort8*)xo + i) = o;
  }
}

// ---------------- kernel 2: fused bf16 MFMA GEMM + BN/ReLU/neighbor-max ----
// K-loop schedule = R11 (proven 44.1 us). ROUND-17 CHANGE: B panel is
// reg-staged DIRECTLY from f32 conv_w with in-register f2bf (bitwise-identical
// to the precast path) + swizzled ds_write_b128 — the 33.5 MB read / 16.8 MB
// write / 16.8 MB re-read cast_w round-trip disappears. T14 split: B loads
// issue BEFORE compute(cur); cvt+ds_write after (latency hides under MFMAs).
// Hazards: writeB targets buf[next], last read two barriers ago; one
// __syncthreads per K-step (drains A-DMA vmcnt + makes B writes visible).
__global__ __launch_bounds__(256, 3) void fused_gemm(
    const unsigned short* __restrict__ Xb, const float* __restrict__ cw,
    const int* __restrict__ nn_idx, const float* __restrict__ conv_b,
    const float* __restrict__ gamma, const float* __restrict__ beta,
    const float* __restrict__ mean, const float* __restrict__ var,
    float* __restrict__ out)
{
  __shared__ __align__(16) char smem[53248];
  // buffer sel at smem + sel*26624: As [80][64] 10240 B, Bs [128][64] 16384 B
  float* Cl  = (float*)smem;                    // [80][128] f32, 40960 B (epilogue reuse)
  int*   idxl = (int*)(smem + 40960);           // [4][200] int — loaded POST-K-loop

  // bijective XCD-chunk swizzle (768 % 8 == 0): XCD c owns 4 consecutive
  // W-panels -> f32 W panel (1 MB) stays resident in that XCD's L2.
  int flat = blockIdx.y * 24 + blockIdx.x;
  int nf = (flat & 7) * 96 + (flat >> 3);
  int bx = nf % 24, by = nf / 24;

  int t = threadIdx.x, lane = t & 63, w = t >> 6;  // w = wr (0..3)
  int m0 = bx * 80, b0 = bx * 4;
  int r0 = by * 128, o0 = by * 64;
  int rowsel = lane & 15, ksel = lane >> 4;

  f32x4 acc[5][2] = {};

  auto stageA = [&](int sel, int k0) {
    unsigned short* Asb = (unsigned short*)(smem + sel*26624);
    #pragma unroll
    for (int i = 0; i < 3; ++i) {                 // A: 640 16B-chunks
      int fl = i*256 + t;
      if (fl < 640) {
        int row = fl >> 3, kc = fl & 7;
        GLOAD_LDS16(Xb + (size_t)(m0 + row) * D_ + k0 + ((kc ^ (row & 7)) << 3),
                    Asb + fl*8);
      }
    }
  };

  // issue 8 float4 loads of this thread's 4 B-chunks (f32, coalesced per
  // 8-thread row group; source chunk index pre-XOR'd so LDS ends up in the
  // same swizzled layout the reads expect)
  auto loadB = [&](float4 (&bf)[8], int k0) {
    #pragma unroll
    for (int i = 0; i < 4; ++i) {
      int fl = i*256 + t;
      int row = fl >> 3, kcg = (fl & 7) ^ (row & 7);
      int r = r0 + row;
      const float* src = cw + (size_t)(r >> 1) * R_ + ((r & 1) << 11) + k0 + kcg*8;
      bf[2*i]   = *(const float4*)src;
      bf[2*i+1] = *(const float4*)(src + 4);
    }
  };

  auto writeB = [&](const float4 (&bf)[8], int sel) {
    unsigned short* Bsb = (unsigned short*)(smem + sel*26624 + 10240);
    #pragma unroll
    for (int i = 0; i < 4; ++i) {
      int fl = i*256 + t;
      const float4& a = bf[2*i];
      const float4& c = bf[2*i+1];
      ushort8 o = { f2bf(a.x), f2bf(a.y), f2bf(a.z), f2bf(a.w),
                    f2bf(c.x), f2bf(c.y), f2bf(c.z), f2bf(c.w) };
      *(ushort8*)(Bsb + fl*8) = o;
    }
  };

  auto compute = [&](int sel) {
    unsigned short* Asb = (unsigned short*)(smem + sel*26624);
    unsigned short* Bsb = (unsigned short*)(smem + sel*26624 + 10240);
    #pragma unroll
    for (int ks = 0; ks < 2; ++ks) {
      int swz = ((ks*4 + ksel) ^ (rowsel & 7)) << 3;   // tile offsets are 16-mult
      bf16x8 a[5], bfr[2];
      #pragma unroll
      for (int mi = 0; mi < 5; ++mi)
        a[mi] = *(const bf16x8*)(Asb + (mi*16 + rowsel)*64 + swz);
      #pragma unroll
      for (int ri = 0; ri < 2; ++ri)
        bfr[ri] = *(const bf16x8*)(Bsb + (w*32 + ri*16 + rowsel)*64 + swz);
      #pragma unroll
      for (int mi = 0; mi < 5; ++mi)
        #pragma unroll
        for (int ri = 0; ri < 2; ++ri)
          acc[mi][ri] = __builtin_amdgcn_mfma_f32_16x16x32_bf16(a[mi], bfr[ri], acc[mi][ri], 0, 0, 0);
    }
  };

  float4 bf[8];
  loadB(bf, 0);
  stageA(0, 0);
  writeB(bf, 0);
  __syncthreads();                                // buf0 ready (A DMA + B writes)
  #pragma unroll 1
  for (int kt = 0; kt < D_/64; ++kt) {
    if (kt + 1 < D_/64) {
      loadB(bf, (kt+1)*64);                       // issue early (T14)
      stageA((kt+1) & 1, (kt+1)*64);
    }
    compute(kt & 1);                              // hides B-load latency
    if (kt + 1 < D_/64) writeB(bf, (kt+1) & 1);   // write late
    __syncthreads();                              // next buf ready
  }

  // ---- fused epilogue (R11) ----
  #pragma unroll
  for (int mi = 0; mi < 5; ++mi)
    #pragma unroll
    for (int ri = 0; ri < 2; ++ri)
      #pragma unroll
      for (int rg = 0; rg < 4; ++rg)
        Cl[(mi*16 + ksel*4 + rg)*128 + w*32 + ri*16 + rowsel] = acc[mi][ri][rg];
  for (int i = t; i < 4*N_*K_; i += 256) idxl[i] = nn_idx[b0*N_*K_ + i];
  __syncthreads();

  int bb = w, oo = lane;               // (batch-in-tile, output-in-tile)
  int og = o0 + oo;
  float invv  = gamma[og] / sqrtf(var[og] + BN_EPS);
  float shift = fmaf(-mean[og], invv, beta[og]);
  float bias  = conv_b[og];
  float best = 0.f;                    // relu identity
  int rbase = bb * N_;
  for (int n = 0; n < N_; ++n) {
    float Pv = Cl[(rbase + n)*128 + oo*2];
    float Qn = Cl[(rbase + n)*128 + oo*2 + 1];
    float aa = Pv - Qn + bias;
    const int* ix = idxl + bb*N_*K_ + n*K_;
    #pragma unroll
    for (int kk = 0; kk < K_; ++kk) {
      int j = ix[kk];
      float v = fmaf(aa + Cl[(rbase + j)*128 + oo*2 + 1], invv, shift);
      best = fmaxf(best, v);
    }
  }
  out[(size_t)(b0 + bb) * D_ + og] = best;
}

extern "C" void kernel_launch(void* const* d_in, const int* in_sizes, int n_in,
                              void* d_out, int out_size, void* d_ws, size_t ws_size,
                              hipStream_t stream)
{
  const float* x      = (const float*)d_in[0];
  const float* conv_w = (const float*)d_in[1];
  const float* conv_b = (const float*)d_in[2];
  const float* gamma  = (const float*)d_in[3];
  const float* beta   = (const float*)d_in[4];
  const float* mean   = (const float*)d_in[5];
  const float* var    = (const float*)d_in[6];

  // workspace: nn_idx 76800 B | Xb bf16 7864320 B   (7.94 MB; Wn eliminated)
  int* nn_idx = (int*)d_ws;
  unsigned short* Xb = (unsigned short*)((char*)d_ws + 76800);

  prep_kernel<<<B_, 512, 0, stream>>>(x, nn_idx, Xb);
  fused_gemm<<<dim3(24, 32), 256, 0, stream>>>(
      Xb, conv_w, nn_idx, conv_b, gamma, beta, mean, var, (float*)d_out);
}